// Round 2
// baseline (376.741 us; speedup 1.0000x reference)
//
#include <hip/hip_runtime.h>
#include <cmath>

// ---------------------------------------------------------------------------
// WireframeDetector: NMS -> top-k 300 junctions -> line sampling (bilinear +
// maxpool) -> 3-layer MLP (fp16 MFMA for the two 1024-wide GEMMs).
// R17: fix R16's T4 violation (drain-to-vmcnt(0) each tile == the m218
//      "8-phase-with-drain0 ~ 1-phase" failure). Now: BK=32, FOUR 32 KiB
//      tile-buffers (128 KiB), 2 phases/tile; during tile t phase 0 issues
//      A-chunks of tile t+2, phase 1 issues B-chunks; tile-boundary wait is
//      vmcnt(4) (tile t+2's 4 loads stay in flight -> 2-tile prefetch lead,
//      never drained to 0 in the main loop). WAR-safe by construction:
//      buffer (t+2)&3 was last read in tile t-2, already fully complete.
//      Swizzled operand layout + epilogues unchanged from R16.
// ---------------------------------------------------------------------------

typedef _Float16 f16;
typedef _Float16 f16x2 __attribute__((ext_vector_type(2)));
typedef _Float16 f16x8 __attribute__((ext_vector_type(8)));
typedef float f32x4 __attribute__((ext_vector_type(4)));

#define HWD 128
#define NPIX 16384            // 128*128
#define TOPK_N 300
#define NLINES 20000
#define M2 20224              // 79 * 256 (padded line count)
#define MH2 158               // M2 / 128 row-halves
#define KTSA 1294336          // MH2 * 8192 f16 elems per 64-wide k-tile (A ops)
#define KTSB 65536            // 8   * 8192 (B ops, N=1024)
#define KDIM 1024
#define NDIM 1024
#define MAXCAND 4096

// Operand layout (A: feats/h1, rows=M2; B: W1T/W2T, rows=1024), f16 elems:
//   idx(row,k) = (k>>6)*KTS + (row>>7)*8192 + ((k>>5)&1)*4096 + (row&127)*32
//              + (((k>>3)&3) ^ ((row>>1)&3))*8 + (k&7)
// Each (64-k-tile, row-half, k-half) 4096-elem chunk is a contiguous 8 KiB
// block that IS the LDS image; the XOR slot swizzle spreads fragment reads
// across bank quads (conflict-free, verified: SQ_LDS_BANK_CONFLICT = 0).

// async global->LDS, 16B per lane; LDS dest = wave-uniform base + lane*16
#define G2L(gp, lp) __builtin_amdgcn_global_load_lds( \
    (const __attribute__((address_space(1))) void*)(gp), \
    (__attribute__((address_space(3))) void*)(lp), 16, 0, 0)

// ---------------------------------------------------------------------------
// Fused preprocessing, one dispatch of 764 blocks:
//   blocks 0..127   : transpose loi [C][H][W] fp32 -> loiT [H][W][C] fp16
//   blocks 128..639 : W1/W2 [K][N] fp32 -> swizzled operand layout fp16
//   blocks 640..703 : 3x3 NMS on jloc, survivors -> cand list
//   blocks 704..763 : zero out[60000] (consumed by gemm2's atomicAdd epilogue)
// ---------------------------------------------------------------------------
__global__ __launch_bounds__(256) void preproc_kernel(
    const float* __restrict__ loi, f16* __restrict__ loiT,
    const float* __restrict__ W1, f16* __restrict__ W1T,
    const float* __restrict__ W2, f16* __restrict__ W2T,
    const float* __restrict__ jloc, unsigned long long* __restrict__ cand,
    int* __restrict__ count, float* __restrict__ out, int out_n)
{
    const int bid = blockIdx.x;
    const int tid = threadIdx.x;
    if (bid < 128) {
        __shared__ f16 t[128 * 130];     // [x][c], +2 pad kills bank conflicts
        const int y = bid;
        #pragma unroll 4
        for (int it = 0; it < 64; ++it) {
            int idx = it * 256 + tid;    // c-major, x fast -> coalesced read
            int c = idx >> 7, x = idx & 127;
            t[x * 130 + c] = (f16)loi[c * NPIX + y * HWD + x];
        }
        __syncthreads();
        #pragma unroll
        for (int it = 0; it < 8; ++it) {
            int j = it * 256 + tid;      // 2048 chunks of 8 f16
            int x = j >> 4, cc = (j & 15) * 8;
            f16x8 v;
            #pragma unroll
            for (int u = 0; u < 8; ++u) v[u] = t[x * 130 + cc + u];
            *(f16x8*)(loiT + (y * HWD + x) * HWD + cc) = v;
        }
    } else if (bid < 640) {
        const int b = bid - 128;         // 0..511
        const float* W = (b < 256) ? W1 : W2;
        f16* Wt = (b < 256) ? W1T : W2T;
        const int bb = b & 255;
        __shared__ f16 t[64 * 66];
        const int k0 = (bb >> 4) * 64;
        const int n0 = (bb & 15) * 64;
        #pragma unroll 4
        for (int it = 0; it < 16; ++it) {
            int i = it * 256 + tid;      // coalesced read over n
            int r = i >> 6, c = i & 63;
            t[c * 66 + r] = (f16)W[(size_t)(k0 + r) * NDIM + n0 + c];
        }
        __syncthreads();
        #pragma unroll
        for (int it = 0; it < 2; ++it) {
            int j = it * 256 + tid;
            int nr = j >> 3, kc8 = (j & 7) * 8;
            f16x8 v;
            #pragma unroll
            for (int u = 0; u < 8; ++u) v[u] = t[nr * 66 + kc8 + u];
            const int row = n0 + nr;     // output col n = B-operand row
            const int k = k0 + kc8;
            const int slot = ((k >> 3) & 3) ^ ((row >> 1) & 3);
            *(f16x8*)(Wt + (size_t)(k >> 6) * KTSB + (size_t)(row >> 7) * 8192
                      + ((k >> 5) & 1) * 4096 + (row & 127) * 32 + slot * 8) = v;
        }
    } else if (bid < 704) {
        const int p = (bid - 640) * 256 + tid;   // 64 blocks x 256 = 16384
        const int y = p >> 7, x = p & 127;
        const float c = jloc[p];
        float m = c;
        for (int dy = -1; dy <= 1; ++dy) {
            int yy = y + dy;
            if (yy < 0 || yy >= HWD) continue;
            for (int dx = -1; dx <= 1; ++dx) {
                int xx = x + dx;
                if (xx < 0 || xx >= HWD) continue;
                m = fmaxf(m, jloc[yy * HWD + xx]);
            }
        }
        if (c == m && c > 0.0f) {
            int pos = atomicAdd(count, 1);
            if (pos < MAXCAND) {
                unsigned int ub = __float_as_uint(c);
                cand[pos] = ((unsigned long long)ub << 32) |
                            (unsigned long long)(0xFFFFFFFFu - (unsigned int)p);
            }
        }
    } else {
        const int base = (bid - 704) * 1024 + tid * 4;   // 60 blocks cover 61440
        #pragma unroll
        for (int u = 0; u < 4; ++u)
            if (base + u < out_n) out[base + u] = 0.f;
    }
}

// ---------------------------------------------------------------------------
// Rank-select top-300, LDS-cached. Keys unique => ranks exact; matches
// jax.lax.top_k order (value desc, index asc).
// ---------------------------------------------------------------------------
__global__ __launch_bounds__(256) void rank_junc_kernel(
    const unsigned long long* __restrict__ cand, const int* __restrict__ count,
    const float* __restrict__ joff, float* __restrict__ juncs /* [300][2] */)
{
    __shared__ unsigned long long keys[MAXCAND];   // 32 KB
    const int n = min(*count, MAXCAND);
    const int t = blockIdx.x * 256 + threadIdx.x;  // 16 blocks = 4096 threads
    for (int i = threadIdx.x; i < n; i += 256)
        keys[i] = cand[i];
    __syncthreads();
    if (t >= n) return;
    const unsigned long long key = keys[t];
    int rank = 0;
    int j = 0;
    for (; j + 4 <= n; j += 4) {
        rank += (keys[j]     > key);
        rank += (keys[j + 1] > key);
        rank += (keys[j + 2] > key);
        rank += (keys[j + 3] > key);
    }
    for (; j < n; ++j) rank += (keys[j] > key);
    if (rank < TOPK_N) {
        unsigned int p = 0xFFFFFFFFu - (unsigned int)(key & 0xFFFFFFFFull);
        // x = idx%w + (sigmoid(joff0)-0.5) + 0.5 = idx%w + sigmoid(joff0)
        float sx = 1.0f / (1.0f + expf(-joff[p]));
        float sy = 1.0f / (1.0f + expf(-joff[NPIX + p]));
        juncs[2 * rank + 0] = (float)(p & 127) + sx;
        juncs[2 * rank + 1] = (float)(p >> 7) + sy;
    }
}

// ---------------------------------------------------------------------------
// Per-line sampling, deduplicated: lanes 0..31 compute the 4 tap offsets +
// weights of the 32 points once into LDS; channel loop (64 lanes, 2 ch each)
// reads them as wave-uniform broadcasts. 4 lines/block (wave per line).
// Output feats in the swizzled GEMM operand layout.
// ---------------------------------------------------------------------------
__global__ __launch_bounds__(256) void sample_kernel(
    const f16* __restrict__ loiT, const float* __restrict__ juncs,
    const int* __restrict__ edge_idx, f16* __restrict__ feats)
{
    const int wv = threadIdx.x >> 6;
    const int l = blockIdx.x * 4 + wv;
    const int lane = threadIdx.x & 63;

    __shared__ int   soff[4][32][4];   // channel-base element offsets
    __shared__ float swt[4][32][4];    // bilinear weights

    if (lane < 32) {
        const int e0 = edge_idx[2 * l], e1 = edge_idx[2 * l + 1];
        const float ux = juncs[2 * e0], uy = juncs[2 * e0 + 1];
        const float vx = juncs[2 * e1], vy = juncs[2 * e1 + 1];
        const int j = lane;
        const float t = (float)j * (1.0f / 31.0f);
        const float px = ux * t + vx * (1.0f - t) - 0.5f;
        const float py = uy * t + vy * (1.0f - t) - 0.5f;
        float fx0 = fminf(fmaxf(floorf(px), 0.0f), 127.0f);
        float fy0 = fminf(fmaxf(floorf(py), 0.0f), 127.0f);
        float fx1 = fminf(fx0 + 1.0f, 127.0f);
        float fy1 = fminf(fy0 + 1.0f, 127.0f);
        int ix0 = (int)fx0, iy0 = (int)fy0, ix1 = (int)fx1, iy1 = (int)fy1;
        soff[wv][j][0] = (iy0 * HWD + ix0) * HWD;
        soff[wv][j][1] = (iy1 * HWD + ix0) * HWD;
        soff[wv][j][2] = (iy0 * HWD + ix1) * HWD;
        soff[wv][j][3] = (iy1 * HWD + ix1) * HWD;
        swt[wv][j][0] = (fy1 - py) * (fx1 - px);
        swt[wv][j][1] = (py - fy0) * (fx1 - px);
        swt[wv][j][2] = (fy1 - py) * (px - fx0);
        swt[wv][j][3] = (py - fy0) * (px - fx0);
    }
    __syncthreads();

    const int c2 = lane * 2;
    f16x8 o0, o1;
    #pragma unroll
    for (int p = 0; p < 8; ++p) {
        float m0 = -INFINITY, m1 = -INFINITY;
        #pragma unroll
        for (int jj = 0; jj < 4; ++jj) {
            const int j = p * 4 + jj;
            const int b00 = soff[wv][j][0], b10 = soff[wv][j][1];
            const int b01 = soff[wv][j][2], b11 = soff[wv][j][3];
            const float w00 = swt[wv][j][0], w10 = swt[wv][j][1];
            const float w01 = swt[wv][j][2], w11 = swt[wv][j][3];
            f16x2 v00 = *(const f16x2*)(loiT + b00 + c2);
            f16x2 v10 = *(const f16x2*)(loiT + b10 + c2);
            f16x2 v01 = *(const f16x2*)(loiT + b01 + c2);
            f16x2 v11 = *(const f16x2*)(loiT + b11 + c2);
            float s0 = (float)v00.x * w00 + (float)v10.x * w10 +
                       (float)v01.x * w01 + (float)v11.x * w11;
            float s1 = (float)v00.y * w00 + (float)v10.y * w10 +
                       (float)v01.y * w01 + (float)v11.y * w11;
            m0 = fmaxf(m0, s0);
            m1 = fmaxf(m1, s1);
        }
        o0[p] = (f16)m0;   // feature k = 16*lane + p
        o1[p] = (f16)m1;   // feature k = 16*lane + 8 + p
    }
    // swizzled operand layout: k0 = 16*lane -> kt = lane>>2, kc = (lane>>1)&1,
    // octets 2*(lane&1) and 2*(lane&1)+1, slot = oct ^ ((row>>1)&3).
    const int rs = (l >> 1) & 3;
    const int oct0 = (lane & 1) * 2;
    f16* base = feats + (size_t)(lane >> 2) * KTSA + (size_t)(l >> 7) * 8192
              + ((lane >> 1) & 1) * 4096 + (l & 127) * 32;
    *(f16x8*)(base + ((oct0 ^ rs) * 8)) = o0;
    *(f16x8*)(base + (((oct0 + 1) ^ rs) * 8)) = o1;
}

// ---------------------------------------------------------------------------
// GEMM: 256x256 tile, 512 threads (2x4 waves, each 128x64 output), BK=32,
// FOUR 32 KiB tile-buffers (128 KiB dynamic LDS), 2 phases per K-tile:
//   phase 0: issue A-chunks of tile t+2; ds_read bf[0..3], af[0..3];
//            barrier; lgkmcnt(0); setprio(1); 16 MFMA (mi 0-3); setprio(0);
//            barrier
//   phase 1: issue B-chunks of tile t+2; ds_read af[4..7]; barrier;
//            lgkmcnt(0); setprio(1); 16 MFMA (mi 4-7); setprio(0);
//            vmcnt(4) [counted: tile t+1 forced complete, tile t+2's 4 loads
//            stay in flight]; barrier
// WAR-safe: buffer (t+2)&3 was last read in tile t-2 (fully complete before
// tile t starts). vmcnt never drains to 0 in the main loop (T4).
// head=0: C = relu(A@Bt^T + bias), stored in swizzled operand layout fp16.
// head=1: v = relu(A@Bt^T + bias); out[m][j] += v . W3  (atomicAdd, + b3 once)
// ---------------------------------------------------------------------------
__global__ __launch_bounds__(512, 2) void gemm_bias_relu_kernel(
    const f16* __restrict__ A, const f16* __restrict__ Bt,
    const float* __restrict__ bias, f16* __restrict__ C,
    const float* __restrict__ W3, const float* __restrict__ b3,
    float* __restrict__ out, int K, int head)
{
    extern __shared__ f16 lds[];                 // 65536 f16 = 128 KiB
    const int tid = threadIdx.x;
    const int wave = tid >> 6, lane = tid & 63;
    const int wm = wave >> 2, wn = wave & 3;     // 2 x 4 wave grid
    const int mblk = blockIdx.x, nblk = blockIdx.y;
    const int m0 = mblk * 256, n0 = nblk * 256;

    const int col16 = lane & 15;
    const int quad = lane >> 4;                  // == k-octet of this lane
    // swizzle slot is lane-constant: oct ^ ((row>>1)&3) with row ≡ col16 mod 16
    const int aoff = col16 * 32 + ((quad ^ ((col16 >> 1) & 3)) * 8);

    f32x4 acc[8][4];
    #pragma unroll
    for (int mi = 0; mi < 8; ++mi)
        #pragma unroll
        for (int ni = 0; ni < 4; ++ni)
            acc[mi][ni] = (f32x4){0.f, 0.f, 0.f, 0.f};

    const size_t abase = (size_t)mblk * 16384;   // 2 row-halves * 8192
    const size_t bbase = (size_t)nblk * 16384;
    const int so = wave * 512 + lane * 8;        // src elem offset (lane*16B)
    const int wb = wave * 512;                   // LDS uniform base per wave
    const int NT = K >> 5;                       // 32 k-tiles of BK=32

    // Tile T occupies buffer T&3 (32 KiB: A 8192 elems + B 8192 elems).
    // Global chunk for tile T, row-half rh: (T>>1)*KTS + rh*8192 + (T&1)*4096.
#define STAGE_A(T) do { \
        const f16* ga_ = A + (size_t)((T) >> 1) * KTSA + abase \
                         + ((T) & 1) * 4096 + so; \
        f16* la_ = lds + ((T) & 3) * 16384; \
        G2L(ga_,        la_ + wb); \
        G2L(ga_ + 8192, la_ + 4096 + wb); \
    } while (0)
#define STAGE_B(T) do { \
        const f16* gb_ = Bt + (size_t)((T) >> 1) * KTSB + bbase \
                         + ((T) & 1) * 4096 + so; \
        f16* lb_ = lds + ((T) & 3) * 16384 + 8192; \
        G2L(gb_,        lb_ + wb); \
        G2L(gb_ + 8192, lb_ + 4096 + wb); \
    } while (0)

    // Prologue: tiles 0 and 1 staged; force tile 0 complete (tile 1's 4 loads
    // may remain outstanding).
    STAGE_A(0); STAGE_B(0);
    STAGE_A(1); STAGE_B(1);
    asm volatile("s_waitcnt vmcnt(4)" ::: "memory");
    __builtin_amdgcn_s_barrier();

    for (int t = 0; t < NT; ++t) {
        f16* sb = lds + (t & 3) * 16384;
        const f16* pA = sb + wm * 4096 + aoff;
        const f16* pB = sb + 8192 + (wn >> 1) * 4096 + (wn & 1) * 2048 + aoff;
        f16x8 bf[4];

        // ---- phase 0: prefetch A(t+2) + bf(all) + af(mi 0..3) ----
        if (t + 2 < NT) STAGE_A(t + 2);
        {
            f16x8 af[4];
            #pragma unroll
            for (int ni = 0; ni < 4; ++ni)
                bf[ni] = *(const f16x8*)(pB + ni * 512);
            #pragma unroll
            for (int i = 0; i < 4; ++i)
                af[i] = *(const f16x8*)(pA + i * 512);
            __builtin_amdgcn_s_barrier();
            asm volatile("s_waitcnt lgkmcnt(0)" ::: "memory");
            __builtin_amdgcn_sched_barrier(0);
            __builtin_amdgcn_s_setprio(1);
            #pragma unroll
            for (int mi = 0; mi < 4; ++mi)
                #pragma unroll
                for (int ni = 0; ni < 4; ++ni)
                    acc[mi][ni] = __builtin_amdgcn_mfma_f32_16x16x32_f16(
                        af[mi], bf[ni], acc[mi][ni], 0, 0, 0);
            __builtin_amdgcn_s_setprio(0);
            __builtin_amdgcn_sched_barrier(0);
            __builtin_amdgcn_s_barrier();
        }
        // ---- phase 1: prefetch B(t+2) + af(mi 4..7) ----
        if (t + 2 < NT) STAGE_B(t + 2);
        {
            f16x8 af[4];
            #pragma unroll
            for (int i = 0; i < 4; ++i)
                af[i] = *(const f16x8*)(pA + (4 + i) * 512);
            __builtin_amdgcn_s_barrier();
            asm volatile("s_waitcnt lgkmcnt(0)" ::: "memory");
            __builtin_amdgcn_sched_barrier(0);
            __builtin_amdgcn_s_setprio(1);
            #pragma unroll
            for (int mi = 0; mi < 4; ++mi)
                #pragma unroll
                for (int ni = 0; ni < 4; ++ni)
                    acc[4 + mi][ni] = __builtin_amdgcn_mfma_f32_16x16x32_f16(
                        af[mi], bf[ni], acc[4 + mi][ni], 0, 0, 0);
            __builtin_amdgcn_s_setprio(0);
            __builtin_amdgcn_sched_barrier(0);
            // Counted wait: next tile (t+1) forced complete; t+2's 4 loads
            // stay in flight. Epilogue tiles (no t+2 staged) drain fully.
            if (t + 2 < NT)
                asm volatile("s_waitcnt vmcnt(4)" ::: "memory");
            else
                asm volatile("s_waitcnt vmcnt(0)" ::: "memory");
            __builtin_amdgcn_s_barrier();
        }
    }
#undef STAGE_A
#undef STAGE_B

    if (!head) {
        #pragma unroll
        for (int ni = 0; ni < 4; ++ni) {
            const int n = n0 + wn * 64 + ni * 16 + col16;
            const float b = bias[n];
            const size_t nb = (size_t)(n >> 6) * KTSA
                            + (size_t)((n >> 5) & 1) * 4096 + (n & 7);
            const int noct = (n >> 3) & 3;
            #pragma unroll
            for (int mi = 0; mi < 8; ++mi) {
                #pragma unroll
                for (int r = 0; r < 4; ++r) {
                    const int m = m0 + wm * 128 + mi * 16 + quad * 4 + r;
                    float v = fmaxf(acc[mi][ni][r] + b, 0.f);
                    C[nb + (size_t)(m >> 7) * 8192 + (size_t)(m & 127) * 32
                      + ((noct ^ ((m >> 1) & 3)) * 8)] = (f16)v;
                }
            }
        }
    } else {
        float bb[4], w3c[4][3];
        #pragma unroll
        for (int ni = 0; ni < 4; ++ni) {
            const int n = n0 + wn * 64 + ni * 16 + col16;
            bb[ni] = bias[n];
            #pragma unroll
            for (int jj = 0; jj < 3; ++jj) w3c[ni][jj] = W3[n * 3 + jj];
        }
        const bool addb3 = (blockIdx.y == 0 && wn == 0);
        #pragma unroll
        for (int mi = 0; mi < 8; ++mi) {
            #pragma unroll
            for (int r = 0; r < 4; ++r) {
                float s0 = 0.f, s1 = 0.f, s2 = 0.f;
                #pragma unroll
                for (int ni = 0; ni < 4; ++ni) {
                    float v = fmaxf(acc[mi][ni][r] + bb[ni], 0.f);
                    s0 += v * w3c[ni][0];
                    s1 += v * w3c[ni][1];
                    s2 += v * w3c[ni][2];
                }
                #pragma unroll
                for (int mask = 1; mask <= 8; mask <<= 1) {
                    s0 += __shfl_xor(s0, mask);
                    s1 += __shfl_xor(s1, mask);
                    s2 += __shfl_xor(s2, mask);
                }
                if (col16 == 0) {
                    const int m = m0 + wm * 128 + mi * 16 + quad * 4 + r;
                    if (m < NLINES) {
                        atomicAdd(&out[m * 3 + 0], s0 + (addb3 ? b3[0] : 0.f));
                        atomicAdd(&out[m * 3 + 1], s1 + (addb3 ? b3[1] : 0.f));
                        atomicAdd(&out[m * 3 + 2], s2 + (addb3 ? b3[2] : 0.f));
                    }
                }
            }
        }
    }
}

// ---------------------------------------------------------------------------
extern "C" void kernel_launch(void* const* d_in, const int* in_sizes, int n_in,
                              void* d_out, int out_size, void* d_ws, size_t ws_size,
                              hipStream_t stream)
{
    const float* jloc = (const float*)d_in[0];
    const float* joff = (const float*)d_in[1];
    const float* loi  = (const float*)d_in[2];
    const int*   eidx = (const int*)d_in[3];
    const float* W1   = (const float*)d_in[4];
    const float* b1   = (const float*)d_in[5];
    const float* W2   = (const float*)d_in[6];
    const float* b2   = (const float*)d_in[7];
    const float* W3   = (const float*)d_in[8];
    const float* b3   = (const float*)d_in[9];
    float* out = (float*)d_out;

    char* ws = (char*)d_ws;
    f16*   loiT  = (f16*)(ws);                            // 4 MB
    f16*   W1T   = (f16*)(ws + ((size_t)4 << 20));        // 2 MB
    f16*   W2T   = (f16*)(ws + ((size_t)6 << 20));        // 2 MB
    float* juncs = (float*)(ws + ((size_t)8 << 20));      // 2.4 KB
    int*   count = (int*)(ws + ((size_t)8 << 20) + 4096);
    unsigned long long* cand =
        (unsigned long long*)(ws + ((size_t)8 << 20) + 8192);  // 32 KB
    f16*   feats = (f16*)(ws + ((size_t)9 << 20));        // 39.5 MB (16*KTSA)
    f16*   h1    = (f16*)(ws + ((size_t)51 << 20));       // 39.5 MB

    static int attr_done = 0;
    if (!attr_done) {
        (void)hipFuncSetAttribute(
            reinterpret_cast<const void*>(&gemm_bias_relu_kernel),
            hipFuncAttributeMaxDynamicSharedMemorySize, 131072);
        attr_done = 1;
    }

    hipMemsetAsync(count, 0, sizeof(int), stream);
    preproc_kernel<<<dim3(764), dim3(256), 0, stream>>>(
        loi, loiT, W1, W1T, W2, W2T, jloc, cand, count, out, out_size);
    rank_junc_kernel<<<dim3(MAXCAND / 256), dim3(256), 0, stream>>>(
        cand, count, joff, juncs);
    sample_kernel<<<dim3(NLINES / 4), dim3(256), 0, stream>>>(loiT, juncs, eidx, feats);
    gemm_bias_relu_kernel<<<dim3(M2 / 256, NDIM / 256), dim3(512), 131072, stream>>>(
        feats, W1T, b1, h1, nullptr, nullptr, nullptr, KDIM, 0);
    gemm_bias_relu_kernel<<<dim3(M2 / 256, NDIM / 256), dim3(512), 131072, stream>>>(
        h1, W2T, b2, nullptr, W3, b3, out, KDIM, 1);
}

// Round 3
// 294.793 us; speedup vs baseline: 1.2780x; 1.2780x over previous
//
#include <hip/hip_runtime.h>
#include <cmath>

// ---------------------------------------------------------------------------
// WireframeDetector: NMS -> top-k 300 junctions -> line sampling (bilinear +
// maxpool) -> 3-layer MLP (fp16 MFMA for the two 1024-wide GEMMs).
// R18: revert to the proven R13 GEMM family (2 blocks/CU, 4 waves, 2x BK=32
//      subtiles per round -> measured 27 GB/s/CU staging delivery), then cut
//      the staged-bytes numerator: BN 128->256 (staged 643 -> 483 MB) and
//      nblk-fastest grid dim3(4,157) so A-panels are re-read within a tight
//      window (HBM-fetch A ~once) and each XCD keeps a fixed 512 KiB B-slice
//      L2-resident. R16/R17's 256^2 1-block/CU phase-locked family measured
//      123-126 us regardless of vmcnt discipline -> abandoned (m232 lesson).
// ---------------------------------------------------------------------------

typedef _Float16 f16;
typedef _Float16 f16x2 __attribute__((ext_vector_type(2)));
typedef _Float16 f16x8 __attribute__((ext_vector_type(8)));
typedef float f32x4 __attribute__((ext_vector_type(4)));

#define HWD 128
#define NPIX 16384            // 128*128
#define TOPK_N 300
#define NLINES 20000
#define MPAD 20096            // 157 * 128
#define KDIM 1024
#define NDIM 1024
#define MAXCAND 4096

// async global->LDS, 16B per lane; LDS dest = wave-uniform base + lane*16
#define G2L(gp, lp) __builtin_amdgcn_global_load_lds( \
    (const __attribute__((address_space(1))) void*)(gp), \
    (__attribute__((address_space(3))) void*)(lp), 16, 0, 0)

// ---------------------------------------------------------------------------
// Fused preprocessing, one dispatch of 764 blocks:
//   blocks 0..127   : transpose loi [C][H][W] fp32 -> loiT [H][W][C] fp16
//   blocks 128..639 : W1/W2 [K][N] fp32 -> K-chunk-tiled fp16
//                     Wt[((k>>5)*1024 + n)*32 + (k&31)]
//   blocks 640..703 : 3x3 NMS on jloc, survivors -> cand list
//   blocks 704..763 : zero out[60000] (consumed by gemm2's atomicAdd epilogue)
// ---------------------------------------------------------------------------
__global__ __launch_bounds__(256) void preproc_kernel(
    const float* __restrict__ loi, f16* __restrict__ loiT,
    const float* __restrict__ W1, f16* __restrict__ W1T,
    const float* __restrict__ W2, f16* __restrict__ W2T,
    const float* __restrict__ jloc, unsigned long long* __restrict__ cand,
    int* __restrict__ count, float* __restrict__ out, int out_n)
{
    const int bid = blockIdx.x;
    const int tid = threadIdx.x;
    if (bid < 128) {
        __shared__ f16 t[128 * 130];     // [x][c], +2 pad kills bank conflicts
        const int y = bid;
        #pragma unroll 4
        for (int it = 0; it < 64; ++it) {
            int idx = it * 256 + tid;    // c-major, x fast -> coalesced read
            int c = idx >> 7, x = idx & 127;
            t[x * 130 + c] = (f16)loi[c * NPIX + y * HWD + x];
        }
        __syncthreads();
        #pragma unroll
        for (int it = 0; it < 8; ++it) {
            int j = it * 256 + tid;      // 2048 chunks of 8 f16
            int x = j >> 4, cc = (j & 15) * 8;
            f16x8 v;
            #pragma unroll
            for (int u = 0; u < 8; ++u) v[u] = t[x * 130 + cc + u];
            *(f16x8*)(loiT + (y * HWD + x) * HWD + cc) = v;
        }
    } else if (bid < 640) {
        const int b = bid - 128;         // 0..511
        const float* W = (b < 256) ? W1 : W2;
        f16* Wt = (b < 256) ? W1T : W2T;
        const int bb = b & 255;
        __shared__ f16 t[64 * 66];
        const int k0 = (bb >> 4) * 64;
        const int n0 = (bb & 15) * 64;
        #pragma unroll 4
        for (int it = 0; it < 16; ++it) {
            int i = it * 256 + tid;      // coalesced read over n
            int r = i >> 6, c = i & 63;
            t[c * 66 + r] = (f16)W[(size_t)(k0 + r) * NDIM + n0 + c];
        }
        __syncthreads();
        #pragma unroll
        for (int it = 0; it < 2; ++it) {
            int j = it * 256 + tid;
            int nr = j >> 3, kc = (j & 7) * 8;
            f16x8 v;
            #pragma unroll
            for (int u = 0; u < 8; ++u) v[u] = t[nr * 66 + kc + u];
            const int kk = k0 + kc;      // multiple of 8
            *(f16x8*)(Wt + ((size_t)(kk >> 5) * NDIM + (n0 + nr)) * 32 + (kk & 31)) = v;
        }
    } else if (bid < 704) {
        const int p = (bid - 640) * 256 + tid;   // 64 blocks x 256 = 16384
        const int y = p >> 7, x = p & 127;
        const float c = jloc[p];
        float m = c;
        for (int dy = -1; dy <= 1; ++dy) {
            int yy = y + dy;
            if (yy < 0 || yy >= HWD) continue;
            for (int dx = -1; dx <= 1; ++dx) {
                int xx = x + dx;
                if (xx < 0 || xx >= HWD) continue;
                m = fmaxf(m, jloc[yy * HWD + xx]);
            }
        }
        if (c == m && c > 0.0f) {
            int pos = atomicAdd(count, 1);
            if (pos < MAXCAND) {
                unsigned int ub = __float_as_uint(c);
                cand[pos] = ((unsigned long long)ub << 32) |
                            (unsigned long long)(0xFFFFFFFFu - (unsigned int)p);
            }
        }
    } else {
        const int base = (bid - 704) * 1024 + tid * 4;   // 60 blocks cover 61440
        #pragma unroll
        for (int u = 0; u < 4; ++u)
            if (base + u < out_n) out[base + u] = 0.f;
    }
}

// ---------------------------------------------------------------------------
// Rank-select top-300, LDS-cached. Keys unique => ranks exact; matches
// jax.lax.top_k order (value desc, index asc).
// ---------------------------------------------------------------------------
__global__ __launch_bounds__(256) void rank_junc_kernel(
    const unsigned long long* __restrict__ cand, const int* __restrict__ count,
    const float* __restrict__ joff, float* __restrict__ juncs /* [300][2] */)
{
    __shared__ unsigned long long keys[MAXCAND];   // 32 KB
    const int n = min(*count, MAXCAND);
    const int t = blockIdx.x * 256 + threadIdx.x;  // 16 blocks = 4096 threads
    for (int i = threadIdx.x; i < n; i += 256)
        keys[i] = cand[i];
    __syncthreads();
    if (t >= n) return;
    const unsigned long long key = keys[t];
    int rank = 0;
    int j = 0;
    for (; j + 4 <= n; j += 4) {
        rank += (keys[j]     > key);
        rank += (keys[j + 1] > key);
        rank += (keys[j + 2] > key);
        rank += (keys[j + 3] > key);
    }
    for (; j < n; ++j) rank += (keys[j] > key);
    if (rank < TOPK_N) {
        unsigned int p = 0xFFFFFFFFu - (unsigned int)(key & 0xFFFFFFFFull);
        // x = idx%w + (sigmoid(joff0)-0.5) + 0.5 = idx%w + sigmoid(joff0)
        float sx = 1.0f / (1.0f + expf(-joff[p]));
        float sy = 1.0f / (1.0f + expf(-joff[NPIX + p]));
        juncs[2 * rank + 0] = (float)(p & 127) + sx;
        juncs[2 * rank + 1] = (float)(p >> 7) + sy;
    }
}

// ---------------------------------------------------------------------------
// Per-line sampling, deduplicated: the 4 tap offsets + 4 weights of each of
// the 32 points depend only on the point, not the channel — lanes 0..31
// compute them ONCE into LDS; the channel loop (all 64 lanes, 2 ch each)
// reads them as wave-uniform broadcasts. 4 lines/block (wave per line).
// Output feats in K-chunk-tiled layout (matches GEMM staging).
// ---------------------------------------------------------------------------
__global__ __launch_bounds__(256) void sample_kernel(
    const f16* __restrict__ loiT, const float* __restrict__ juncs,
    const int* __restrict__ edge_idx, f16* __restrict__ feats)
{
    const int wv = threadIdx.x >> 6;
    const int l = blockIdx.x * 4 + wv;
    const int lane = threadIdx.x & 63;

    __shared__ int   soff[4][32][4];   // channel-base element offsets
    __shared__ float swt[4][32][4];    // bilinear weights

    if (lane < 32) {
        const int e0 = edge_idx[2 * l], e1 = edge_idx[2 * l + 1];
        const float ux = juncs[2 * e0], uy = juncs[2 * e0 + 1];
        const float vx = juncs[2 * e1], vy = juncs[2 * e1 + 1];
        const int j = lane;
        const float t = (float)j * (1.0f / 31.0f);
        const float px = ux * t + vx * (1.0f - t) - 0.5f;
        const float py = uy * t + vy * (1.0f - t) - 0.5f;
        float fx0 = fminf(fmaxf(floorf(px), 0.0f), 127.0f);
        float fy0 = fminf(fmaxf(floorf(py), 0.0f), 127.0f);
        float fx1 = fminf(fx0 + 1.0f, 127.0f);
        float fy1 = fminf(fy0 + 1.0f, 127.0f);
        int ix0 = (int)fx0, iy0 = (int)fy0, ix1 = (int)fx1, iy1 = (int)fy1;
        soff[wv][j][0] = (iy0 * HWD + ix0) * HWD;
        soff[wv][j][1] = (iy1 * HWD + ix0) * HWD;
        soff[wv][j][2] = (iy0 * HWD + ix1) * HWD;
        soff[wv][j][3] = (iy1 * HWD + ix1) * HWD;
        swt[wv][j][0] = (fy1 - py) * (fx1 - px);
        swt[wv][j][1] = (py - fy0) * (fx1 - px);
        swt[wv][j][2] = (fy1 - py) * (px - fx0);
        swt[wv][j][3] = (py - fy0) * (px - fx0);
    }
    __syncthreads();

    const int c2 = lane * 2;
    f16x8 o0, o1;
    #pragma unroll
    for (int p = 0; p < 8; ++p) {
        float m0 = -INFINITY, m1 = -INFINITY;
        #pragma unroll
        for (int jj = 0; jj < 4; ++jj) {
            const int j = p * 4 + jj;
            const int b00 = soff[wv][j][0], b10 = soff[wv][j][1];
            const int b01 = soff[wv][j][2], b11 = soff[wv][j][3];
            const float w00 = swt[wv][j][0], w10 = swt[wv][j][1];
            const float w01 = swt[wv][j][2], w11 = swt[wv][j][3];
            f16x2 v00 = *(const f16x2*)(loiT + b00 + c2);
            f16x2 v10 = *(const f16x2*)(loiT + b10 + c2);
            f16x2 v01 = *(const f16x2*)(loiT + b01 + c2);
            f16x2 v11 = *(const f16x2*)(loiT + b11 + c2);
            float s0 = (float)v00.x * w00 + (float)v10.x * w10 +
                       (float)v01.x * w01 + (float)v11.x * w11;
            float s1 = (float)v00.y * w00 + (float)v10.y * w10 +
                       (float)v01.y * w01 + (float)v11.y * w11;
            m0 = fmaxf(m0, s0);
            m1 = fmaxf(m1, s1);
        }
        o0[p] = (f16)m0;   // feature k = 16*lane + p
        o1[p] = (f16)m1;   // feature k = 16*lane + 8 + p
    }
    // tiled: (l, k) -> ((k>>5)*MPAD + l)*32 + (k&31); k-chunk = lane>>1,
    // within-chunk = (lane&1)*16.
    f16* dst = feats + ((size_t)(lane >> 1) * MPAD + l) * 32 + (lane & 1) * 16;
    *(f16x8*)(dst) = o0;
    *(f16x8*)(dst + 8) = o1;
}

// ---------------------------------------------------------------------------
// GEMM: 128x256 tile, 256 threads (2x2 waves of 64x128 subtiles). Two BK=32
// subtiles per round (one vmcnt(0)+barrier drain per 64 MFMAs/wave), operands
// in K-chunk-tiled layout (each staged tile contiguous; G2L = 1KB bursts).
// LDS [row][32] f16 (proven fragment/bank behavior), 48 KiB -> 2 blocks/CU.
// Grid dim3(4,157), x = nblk FAST: consecutive blocks share the A-panel
// (HBM-fetch A once) and each XCD sees a fixed nblk (B-slice L2-resident).
// head=0: C = relu(A@Bt^T + bias), stored K-chunk-tiled fp16.
// head=1: v = relu(A@Bt^T + bias); out[m][j] += v . W3  (atomicAdd, + b3 once)
// ---------------------------------------------------------------------------
__global__ __launch_bounds__(256, 2) void gemm_bias_relu_kernel(
    const f16* __restrict__ A, const f16* __restrict__ Bt,
    const float* __restrict__ bias, f16* __restrict__ C,
    const float* __restrict__ W3, const float* __restrict__ b3,
    float* __restrict__ out, int K, int head)
{
    const int tid = threadIdx.x;
    const int wave = tid >> 6, lane = tid & 63;
    const int wm = wave >> 1, wn = wave & 1;
    const int m0 = blockIdx.y * 128;             // y = mblk (slow)
    const int n0 = blockIdx.x * 256;             // x = nblk (fast)

    __shared__ f16 sA0[128 * 32];                //  8 KiB
    __shared__ f16 sA1[128 * 32];
    __shared__ f16 sB0[256 * 32];                // 16 KiB
    __shared__ f16 sB1[256 * 32];

    f32x4 acc[4][8];
    #pragma unroll
    for (int mi = 0; mi < 4; ++mi)
        #pragma unroll
        for (int ni = 0; ni < 8; ++ni)
            acc[mi][ni] = (f32x4){0.f, 0.f, 0.f, 0.f};

    // Tiled staging: k-chunk c of A-tile = contiguous 4096 f16 at
    // A + (c*MPAD + m0)*32 (8 segs of 1KB); B-tile = 8192 f16 (16 segs).
    // Wave w stages A segs {w, w+4}, B segs {w, w+4, w+8, w+12};
    // lane i deposits seg_base + i*16B. Global order == LDS order.
    const size_t strideA = (size_t)MPAD * 32;   // f16 per k-chunk
    const size_t strideB = (size_t)NDIM * 32;
    const f16* gA = A + (size_t)m0 * 32 + wave * 512 + lane * 8;
    const f16* gB = Bt + (size_t)n0 * 32 + wave * 512 + lane * 8;
    const int so = wave * 512;                  // + lane*16B implicit

    const int col16 = lane & 15;
    const int kq = (lane >> 4) * 8;

    const int NC = K >> 5;                      // 32 k-chunks
    for (int c0 = 0; c0 < NC; c0 += 2) {
        const f16* a0 = gA + (size_t)c0 * strideA;
        const f16* a1 = a0 + strideA;
        const f16* b0 = gB + (size_t)c0 * strideB;
        const f16* b1 = b0 + strideB;
        __syncthreads();                      // prev round's LDS reads complete
        G2L(a0, sA0 + so);
        G2L(a0 + 2048, sA0 + so + 2048);
        G2L(a1, sA1 + so);
        G2L(a1 + 2048, sA1 + so + 2048);
        G2L(b0, sB0 + so);
        G2L(b0 + 2048, sB0 + so + 2048);
        G2L(b0 + 4096, sB0 + so + 4096);
        G2L(b0 + 6144, sB0 + so + 6144);
        G2L(b1, sB1 + so);
        G2L(b1 + 2048, sB1 + so + 2048);
        G2L(b1 + 4096, sB1 + so + 4096);
        G2L(b1 + 6144, sB1 + so + 6144);
        __builtin_amdgcn_s_waitcnt(0x0f70);   // vmcnt(0): own DMA done
        __syncthreads();                      // all waves' DMA done

        {
            f16x8 af[4], bf[8];
            #pragma unroll
            for (int i = 0; i < 4; ++i)
                af[i] = *(const f16x8*)(sA0 + (wm * 64 + i * 16 + col16) * 32 + kq);
            #pragma unroll
            for (int i = 0; i < 8; ++i)
                bf[i] = *(const f16x8*)(sB0 + (wn * 128 + i * 16 + col16) * 32 + kq);
            #pragma unroll
            for (int mi = 0; mi < 4; ++mi)
                #pragma unroll
                for (int ni = 0; ni < 8; ++ni)
                    acc[mi][ni] = __builtin_amdgcn_mfma_f32_16x16x32_f16(
                        af[mi], bf[ni], acc[mi][ni], 0, 0, 0);
        }
        {
            f16x8 af[4], bf[8];
            #pragma unroll
            for (int i = 0; i < 4; ++i)
                af[i] = *(const f16x8*)(sA1 + (wm * 64 + i * 16 + col16) * 32 + kq);
            #pragma unroll
            for (int i = 0; i < 8; ++i)
                bf[i] = *(const f16x8*)(sB1 + (wn * 128 + i * 16 + col16) * 32 + kq);
            #pragma unroll
            for (int mi = 0; mi < 4; ++mi)
                #pragma unroll
                for (int ni = 0; ni < 8; ++ni)
                    acc[mi][ni] = __builtin_amdgcn_mfma_f32_16x16x32_f16(
                        af[mi], bf[ni], acc[mi][ni], 0, 0, 0);
        }
    }

    const int quad = lane >> 4;
    if (!head) {
        #pragma unroll
        for (int ni = 0; ni < 8; ++ni) {
            const int n = n0 + wn * 128 + ni * 16 + col16;
            const float b = bias[n];
            const size_t cb = ((size_t)(n >> 5) * MPAD) * 32 + (n & 31);
            #pragma unroll
            for (int mi = 0; mi < 4; ++mi) {
                #pragma unroll
                for (int r = 0; r < 4; ++r) {
                    const int m = m0 + wm * 64 + mi * 16 + quad * 4 + r;
                    float v = fmaxf(acc[mi][ni][r] + b, 0.f);
                    C[cb + (size_t)m * 32] = (f16)v;   // K-chunk-tiled
                }
            }
        }
    } else {
        float bb[8], w3c[8][3];
        #pragma unroll
        for (int ni = 0; ni < 8; ++ni) {
            const int n = n0 + wn * 128 + ni * 16 + col16;
            bb[ni] = bias[n];
            #pragma unroll
            for (int jj = 0; jj < 3; ++jj) w3c[ni][jj] = W3[n * 3 + jj];
        }
        const bool addb3 = (blockIdx.x == 0 && wn == 0);
        #pragma unroll
        for (int mi = 0; mi < 4; ++mi) {
            #pragma unroll
            for (int r = 0; r < 4; ++r) {
                float s0 = 0.f, s1 = 0.f, s2 = 0.f;
                #pragma unroll
                for (int ni = 0; ni < 8; ++ni) {
                    float v = fmaxf(acc[mi][ni][r] + bb[ni], 0.f);
                    s0 += v * w3c[ni][0];
                    s1 += v * w3c[ni][1];
                    s2 += v * w3c[ni][2];
                }
                #pragma unroll
                for (int mask = 1; mask <= 8; mask <<= 1) {
                    s0 += __shfl_xor(s0, mask);
                    s1 += __shfl_xor(s1, mask);
                    s2 += __shfl_xor(s2, mask);
                }
                if (col16 == 0) {
                    const int m = m0 + wm * 64 + mi * 16 + quad * 4 + r;
                    if (m < NLINES) {
                        atomicAdd(&out[m * 3 + 0], s0 + (addb3 ? b3[0] : 0.f));
                        atomicAdd(&out[m * 3 + 1], s1 + (addb3 ? b3[1] : 0.f));
                        atomicAdd(&out[m * 3 + 2], s2 + (addb3 ? b3[2] : 0.f));
                    }
                }
            }
        }
    }
}

// ---------------------------------------------------------------------------
extern "C" void kernel_launch(void* const* d_in, const int* in_sizes, int n_in,
                              void* d_out, int out_size, void* d_ws, size_t ws_size,
                              hipStream_t stream)
{
    const float* jloc = (const float*)d_in[0];
    const float* joff = (const float*)d_in[1];
    const float* loi  = (const float*)d_in[2];
    const int*   eidx = (const int*)d_in[3];
    const float* W1   = (const float*)d_in[4];
    const float* b1   = (const float*)d_in[5];
    const float* W2   = (const float*)d_in[6];
    const float* b2   = (const float*)d_in[7];
    const float* W3   = (const float*)d_in[8];
    const float* b3   = (const float*)d_in[9];
    float* out = (float*)d_out;

    char* ws = (char*)d_ws;
    f16*   loiT  = (f16*)(ws);                            // 4 MB
    f16*   W1T   = (f16*)(ws + ((size_t)4 << 20));        // 2 MB
    f16*   W2T   = (f16*)(ws + ((size_t)6 << 20));        // 2 MB
    float* juncs = (float*)(ws + ((size_t)8 << 20));      // 2.4 KB
    int*   count = (int*)(ws + ((size_t)8 << 20) + 4096);
    unsigned long long* cand =
        (unsigned long long*)(ws + ((size_t)8 << 20) + 8192);  // 32 KB
    f16*   feats = (f16*)(ws + ((size_t)9 << 20));        // 40 MB (tiled MPADx1024)
    f16*   h1    = (f16*)(ws + ((size_t)51 << 20));       // 40 MB (tiled)

    hipMemsetAsync(count, 0, sizeof(int), stream);
    preproc_kernel<<<dim3(764), dim3(256), 0, stream>>>(
        loi, loiT, W1, W1T, W2, W2T, jloc, cand, count, out, out_size);
    rank_junc_kernel<<<dim3(MAXCAND / 256), dim3(256), 0, stream>>>(
        cand, count, joff, juncs);
    sample_kernel<<<dim3(NLINES / 4), dim3(256), 0, stream>>>(loiT, juncs, eidx, feats);
    gemm_bias_relu_kernel<<<dim3(NDIM / 256, MPAD / 128), dim3(256), 0, stream>>>(
        feats, W1T, b1, h1, nullptr, nullptr, nullptr, KDIM, 0);
    gemm_bias_relu_kernel<<<dim3(NDIM / 256, MPAD / 128), dim3(256), 0, stream>>>(
        h1, W2T, b2, nullptr, W3, b3, out, KDIM, 1);
}